// Round 5
// baseline (575.504 us; speedup 1.0000x reference)
//
#include <hip/hip_runtime.h>

// receptive_attention: out[b,h,i,j] = (|i-j| <= 128) ? dot(q[i,:], k[j,:]) : 0
// B=2 H=16 L=2048 D=64 fp32.
//
// R8: TWO-DISPATCH SPLIT (discriminating experiment, not an optimization bet).
// Evidence so far: R3/R6/R7 all ~207-215us kernel slice at ~2.6 TB/s effective
// despite 4x LDS-instr changes (R6) and fill-identical monotone store streams
// (R7); the harness fill does 6.2 TB/s with FETCH~0 on the same buffer.
// Surviving theories: (a) band/zero co-residency degrades the store stream,
// (b) hidden traffic amplification, (c) kernel is already near the ~95us
// floor and the rest is fixed harness cost. R8 isolates (a): dispatch 1 =
// R6's band path VERBATIM (LDS/compute blocks only), dispatch 2 = R3's zero
// path VERBATIM (pure contiguous zero stores - a literal fill clone).
// Pre-committed read: ~500-525 -> mixing was the wall; ~554 -> traffic/harness
// bound (declare roofline); >=565 -> overlap was helping (also roofline).
// MEASURED-BAD, do not reintroduce: __builtin_nontemporal_store (R2: RMW
// amplification), scalar-write transposed-K staging (8-way conflicts), R5/R7
// 512-1024-thr strip-monolithic compute (567/555us), >64KB static __shared__
// (R4: container-killing launch failure).

constexpr int L = 2048;
constexpr int D = 64;
constexpr int R = 128;
constexpr int TILE = 64;
constexpr int NT = L / TILE;        // 32

// ---------------- dispatch 1: band tiles (R6 path, verbatim) ----------------
__global__ __launch_bounds__(256, 4)
void band_kernel(const float* __restrict__ q,
                 const float* __restrict__ k,
                 float* __restrict__ out) {
    const int ti   = blockIdx.x;    // 64-row strip
    const int kind = blockIdx.y;    // 0..4 -> tj = ti + kind - 2
    const int bh   = blockIdx.z;
    const int t    = threadIdx.x;

    const int tj = ti + kind - 2;
    if (tj < 0 || tj >= NT) return;

    float* outStrip = out + (size_t)bh * L * L + (size_t)ti * TILE * L;

    // Swizzled tiles, stride 64 (32 KB total). Element (row, d) lives at
    // word row*64 + 4*(((d>>2) ^ (row>>2)) & 15) + (d&3).
    __shared__ __align__(16) float Qs[TILE * 64];
    __shared__ __align__(16) float Ks[TILE * 64];

    const float* qTile = q + ((size_t)bh * L + (size_t)ti * TILE) * D;
    const float* kTile = k + ((size_t)bh * L + (size_t)tj * TILE) * D;

    #pragma unroll
    for (int it = 0; it < 4; ++it) {
        int idx  = t + it * 256;
        int row  = idx >> 4;          // 0..63
        int col4 = idx & 15;          // 16B-block index within row
        float4 qv = *reinterpret_cast<const float4*>(qTile + row * D + col4 * 4);
        float4 kv = *reinterpret_cast<const float4*>(kTile + row * D + col4 * 4);
        int wblk = (col4 ^ (row >> 2)) & 15;
        *reinterpret_cast<float4*>(&Qs[row * 64 + wblk * 4]) = qv;
        *reinterpret_cast<float4*>(&Ks[row * 64 + wblk * 4]) = kv;
    }
    __syncthreads();

    const int tr = (t >> 4) * 4;   // micro-tile base row
    const int tc = (t & 15) * 4;   // micro-tile base col
    const int xq = (t >> 4) & 15;  // (row>>2) for all 4 q rows
    const int xk = t & 15;         // (col>>2) for all 4 k cols

    float acc[4][4] = {};
    #pragma unroll 4
    for (int b = 0; b < 16; ++b) {  // d0 = 4*b
        float4 qv[4], kv[4];
        const int qb = ((b ^ xq) & 15) * 4;
        const int kb = ((b ^ xk) & 15) * 4;
        #pragma unroll
        for (int r = 0; r < 4; ++r)
            qv[r] = *reinterpret_cast<const float4*>(&Qs[(tr + r) * 64 + qb]);
        #pragma unroll
        for (int c = 0; c < 4; ++c)
            kv[c] = *reinterpret_cast<const float4*>(&Ks[(tc + c) * 64 + kb]);
        #pragma unroll
        for (int rr = 0; rr < 4; ++rr) {
            #pragma unroll
            for (int cc = 0; cc < 4; ++cc) {
                // d-order preserved: four separate += (bit-exact)
                acc[rr][cc] += qv[rr].x * kv[cc].x;
                acc[rr][cc] += qv[rr].y * kv[cc].y;
                acc[rr][cc] += qv[rr].z * kv[cc].z;
                acc[rr][cc] += qv[rr].w * kv[cc].w;
            }
        }
    }

    float* outTile = outStrip + tj * TILE;
    const int gi0 = ti * TILE + tr;
    const int gj0 = tj * TILE + tc;
    #pragma unroll
    for (int rr = 0; rr < 4; ++rr) {
        int gi = gi0 + rr;
        float4 v;
        float* vp = &v.x;
        #pragma unroll
        for (int cc = 0; cc < 4; ++cc) {
            int gj = gj0 + cc;
            int diff = gi - gj;
            if (diff < 0) diff = -diff;
            vp[cc] = (diff <= R) ? acc[rr][cc] : 0.f;
        }
        *reinterpret_cast<float4*>(outTile + (size_t)(tr + rr) * L + tc) = v;
    }
}

// ---------------- dispatch 2: zero region (R3 path, verbatim) ----------------
__global__ __launch_bounds__(256, 4)
void zero_kernel(float* __restrict__ out) {
    const int ti  = blockIdx.x;     // 64-row strip
    const int seg = blockIdx.y;     // 0..3 -> rows [16*seg, +16)
    const int bh  = blockIdx.z;
    const int t   = threadIdx.x;

    const int jt_lo = (ti - 2 > 0) ? (ti - 2) : 0;
    const int jt_hi = (ti + 2 < NT - 1) ? (ti + 2) : (NT - 1);

    float* outStrip = out + (size_t)bh * L * L + (size_t)ti * TILE * L;

    const int r0  = seg * 16;
    const int wl4 = (jt_lo * TILE) / 4;                  // left-run float4s
    const int rb  = (jt_hi + 1) * TILE;                  // right-run start col
    const int nz4 = (L - (jt_hi - jt_lo + 1) * TILE) / 4;
    const float4 z = make_float4(0.f, 0.f, 0.f, 0.f);
    for (int r = 0; r < 16; ++r) {
        float* orow = outStrip + (size_t)(r0 + r) * L;
        for (int f = t; f < nz4; f += 256) {
            int col = (f < wl4) ? (f * 4) : (rb + (f - wl4) * 4);
            *reinterpret_cast<float4*>(orow + col) = z;
        }
    }
}

extern "C" void kernel_launch(void* const* d_in, const int* in_sizes, int n_in,
                              void* d_out, int out_size, void* d_ws, size_t ws_size,
                              hipStream_t stream) {
    const float* q = (const float*)d_in[0];
    const float* k = (const float*)d_in[1];
    float* out = (float*)d_out;

    dim3 gband(NT, 5, 32);  // band tiles only (LDS + compute blocks)
    band_kernel<<<gband, 256, 0, stream>>>(q, k, out);

    dim3 gzero(NT, 4, 32);  // pure-store fill clone, disjoint region
    zero_kernel<<<gzero, 256, 0, stream>>>(out);
}